// Round 1
// baseline (725.738 us; speedup 1.0000x reference)
//
#include <hip/hip_runtime.h>

typedef __attribute__((ext_vector_type(8))) short bf16x8;
typedef __attribute__((ext_vector_type(4))) float f32x4;
typedef __attribute__((ext_vector_type(4))) short s16x4;

#define DEV __device__ __forceinline__

DEV short f2bf(float f) {
  union { float f; unsigned u; } v; v.f = f;
  unsigned r = v.u + 0x7fffu + ((v.u >> 16) & 1u);
  return (short)(r >> 16);
}

// ---------------- transpose fp32 -> bf16: out[n][k] = bf16(in[k][n]) ----------------
__global__ __launch_bounds__(256) void transpose_to_bf16(
    const float* __restrict__ in, long ld, short* __restrict__ out, int K) {
  __shared__ short tile[64][66];
  long k0 = blockIdx.x * 64L, n0 = blockIdx.y * 64L;
  int t = threadIdx.x;
  {
    int kl = t >> 4, nl4 = (t & 15) * 4;
#pragma unroll
    for (int i = 0; i < 4; i++) {
      int k = kl + i * 16;
      float4 v = *(const float4*)(in + (k0 + k) * ld + n0 + nl4);
      s16x4 w; w.x = f2bf(v.x); w.y = f2bf(v.y); w.z = f2bf(v.z); w.w = f2bf(v.w);
      *(s16x4*)&tile[k][nl4] = w;
    }
  }
  __syncthreads();
  {
    int nl = t >> 4, kl4 = (t & 15) * 4;
#pragma unroll
    for (int i = 0; i < 4; i++) {
      int n = nl + i * 16;
      s16x4 w;
      w.x = tile[kl4 + 0][n]; w.y = tile[kl4 + 1][n];
      w.z = tile[kl4 + 2][n]; w.w = tile[kl4 + 3][n];
      *(s16x4*)(out + (n0 + n) * (long)K + k0 + kl4) = w;
    }
  }
}

// ---------------- GEMM: C[M x N] = A[M x K] * Bt[N x K]^T ----------------
// A fp32 (convert on the fly) or bf16; Bt bf16 row-major [N][K]; C fp32.
// Block tile 64x64, BK=64, 256 threads (2x2 waves, each wave 32x32).
// LDS in MFMA-fragment order: frag-block fb = s*4 + tile16 (s = k-step of 32),
// byte addr = fb*1088 + lane*16 + (lane>>4)*16  (pad breaks write conflicts).
template <bool AF32>
__global__ __launch_bounds__(256) void gemm_bt(
    const void* __restrict__ Ap, const short* __restrict__ Bt,
    float* __restrict__ C, int N, int K) {
  __shared__ short As[8 * 544];
  __shared__ short Bs[8 * 544];
  int t = threadIdx.x;
  long m0 = blockIdx.y * 64L, n0 = blockIdx.x * 64L;
  int lane = t & 63, quad = lane >> 4, m16 = lane & 15;
  int wave = t >> 6, wm = wave & 1, wn = wave >> 1;
  f32x4 acc[2][2] = {};
  int r = t >> 3, c = t & 7;  // staging coords: rows 0..31(+32), k-chunks of 8

  for (int k0 = 0; k0 < K; k0 += 64) {
    __syncthreads();
#pragma unroll
    for (int half = 0; half < 2; half++) {
      int rr = r + half * 32;
      int fb = (c >> 2) * 4 + (rr >> 4);
      int pos = (c & 3) * 16 + (rr & 15);
      int off = fb * 544 + pos * 8 + (pos >> 4) * 8;  // in shorts
      bf16x8 av;
      if (AF32) {
        const float* src = (const float*)Ap + (m0 + rr) * (long)K + k0 + c * 8;
        float4 x = *(const float4*)src;
        float4 y = *(const float4*)(src + 4);
        av[0] = f2bf(x.x); av[1] = f2bf(x.y); av[2] = f2bf(x.z); av[3] = f2bf(x.w);
        av[4] = f2bf(y.x); av[5] = f2bf(y.y); av[6] = f2bf(y.z); av[7] = f2bf(y.w);
      } else {
        av = *(const bf16x8*)((const short*)Ap + (m0 + rr) * (long)K + k0 + c * 8);
      }
      *(bf16x8*)&As[off] = av;
      *(bf16x8*)&Bs[off] = *(const bf16x8*)(Bt + (n0 + rr) * (long)K + k0 + c * 8);
    }
    __syncthreads();
#pragma unroll
    for (int s = 0; s < 2; s++) {
      int lo = lane * 8 + quad * 8;
      bf16x8 a0 = *(bf16x8*)&As[(s * 4 + wm * 2 + 0) * 544 + lo];
      bf16x8 a1 = *(bf16x8*)&As[(s * 4 + wm * 2 + 1) * 544 + lo];
      bf16x8 b0 = *(bf16x8*)&Bs[(s * 4 + wn * 2 + 0) * 544 + lo];
      bf16x8 b1 = *(bf16x8*)&Bs[(s * 4 + wn * 2 + 1) * 544 + lo];
      acc[0][0] = __builtin_amdgcn_mfma_f32_16x16x32_bf16(a0, b0, acc[0][0], 0, 0, 0);
      acc[0][1] = __builtin_amdgcn_mfma_f32_16x16x32_bf16(a0, b1, acc[0][1], 0, 0, 0);
      acc[1][0] = __builtin_amdgcn_mfma_f32_16x16x32_bf16(a1, b0, acc[1][0], 0, 0, 0);
      acc[1][1] = __builtin_amdgcn_mfma_f32_16x16x32_bf16(a1, b1, acc[1][1], 0, 0, 0);
    }
  }
#pragma unroll
  for (int i = 0; i < 2; i++)
#pragma unroll
    for (int j = 0; j < 2; j++)
#pragma unroll
      for (int rg = 0; rg < 4; rg++) {
        long m = m0 + (wm * 2 + i) * 16 + quad * 4 + rg;
        long n = n0 + (wn * 2 + j) * 16 + m16;
        C[m * (long)N + n] = acc[i][j][rg];
      }
}

// ---------------- double RMSNorm + RoPE + scale on Q ----------------
// one wave per (row, head); lane holds d and d+64
__global__ __launch_bounds__(256) void q_norm_rope(
    const float* __restrict__ qtmp, const float* __restrict__ qw,
    const float* __restrict__ cosp, const float* __restrict__ sinp,
    short* __restrict__ qr) {
  int wid = blockIdx.x * 4 + (threadIdx.x >> 6);
  int lane = threadIdx.x & 63;
  int rrow = wid >> 5, h = wid & 31;
  long base = (long)rrow * 4096 + h * 128;
  float x1 = qtmp[base + lane], x2 = qtmp[base + 64 + lane];
  float w1 = qw[lane], w2 = qw[64 + lane];
  float ss = x1 * x1 + x2 * x2;
#pragma unroll
  for (int m = 1; m < 64; m <<= 1) ss += __shfl_xor(ss, m, 64);
  float rs = rsqrtf(ss * (1.0f / 128.0f) + 1e-6f);
  float y1 = x1 * rs * w1, y2 = x2 * rs * w2;
  float ss2 = y1 * y1 + y2 * y2;
#pragma unroll
  for (int m = 1; m < 64; m <<= 1) ss2 += __shfl_xor(ss2, m, 64);
  float rs2 = rsqrtf(ss2 * (1.0f / 128.0f) + 1e-6f);
  float z1 = y1 * rs2 * w1, z2 = y2 * rs2 * w2;
  long cpos = (long)(4096 + (rrow & 63)) * 128;
  float c1 = cosp[cpos + lane], c2 = cosp[cpos + 64 + lane];
  float s1 = sinp[cpos + lane], s2 = sinp[cpos + 64 + lane];
  const float scale = 0.08838834764831845f;  // 1/sqrt(128)
  float o1 = (z1 * c1 - z2 * s1) * scale;
  float o2 = (z2 * c2 + z1 * s2) * scale;
  qr[base + lane] = f2bf(o1);
  qr[base + 64 + lane] = f2bf(o2);
}

// ---------------- flash attention, split-K over key dim ----------------
#define ATT_SPLIT 5
#define ATT_LKV 832
#define ATT_TILES 13

__global__ __launch_bounds__(256) void attn_kernel(
    const short* __restrict__ qr, const float* __restrict__ th,
    const float* __restrict__ hs, const float* __restrict__ cosp,
    const float* __restrict__ sinp, float* __restrict__ part,
    float* __restrict__ mstat, float* __restrict__ lstat) {
  __shared__ short Ks[64 * 136];   // roped K, [l][d], pad 136
  __shared__ short Vt[128 * 80];   // raw V transposed, [d][l], pad 80
  __shared__ short Ps[64 * 72];    // P (C-layout -> A-layout round trip)
  int bh = blockIdx.x, split = blockIdx.y;
  int b = bh >> 5, h = bh & 31;
  int t = threadIdx.x;
  int wave = t >> 6, lane = t & 63, quad = lane >> 4, m16 = lane & 15;

  // Q A-fragments (wave owns q rows wave*16..wave*16+15); Q pre-scaled/roped/normed
  bf16x8 aq[4];
  {
    const short* qrow = qr + (long)(b * 64 + wave * 16 + m16) * 4096 + h * 128;
#pragma unroll
    for (int s = 0; s < 4; s++) aq[s] = *(const bf16x8*)(qrow + s * 32 + quad * 8);
  }
  float mi[4] = {-INFINITY, -INFINITY, -INFINITY, -INFINITY};
  float li[4] = {0.f, 0.f, 0.f, 0.f};
  f32x4 oacc[8] = {};

  int srow = t >> 2;  // staging: 4 threads per key-row
  int sc = t & 3;

  for (int tile = 0; tile < ATT_TILES; tile++) {
    int l0 = split * ATT_LKV + tile * 64;
    __syncthreads();
    {
      int lg = l0 + srow;
      const float* kvrow = (lg < 4096)
          ? th + ((long)b * 4096 + lg) * 4096 + h * 128
          : hs + ((long)b * 64 + (lg - 4096)) * 4096 + h * 128;
      const float* crow = cosp + (long)lg * 128;
      const float* srw = sinp + (long)lg * 128;
#pragma unroll
      for (int i = 0; i < 2; i++) {
        int c = sc + 4 * i;
        int d1 = c * 8, d2 = d1 + 64;
        alignas(16) float xa[8], xb[8], cA[8], sA[8], cB[8], sB[8];
        *(float4*)&xa[0] = *(const float4*)(kvrow + d1);
        *(float4*)&xa[4] = *(const float4*)(kvrow + d1 + 4);
        *(float4*)&xb[0] = *(const float4*)(kvrow + d2);
        *(float4*)&xb[4] = *(const float4*)(kvrow + d2 + 4);
        *(float4*)&cA[0] = *(const float4*)(crow + d1);
        *(float4*)&cA[4] = *(const float4*)(crow + d1 + 4);
        *(float4*)&cB[0] = *(const float4*)(crow + d2);
        *(float4*)&cB[4] = *(const float4*)(crow + d2 + 4);
        *(float4*)&sA[0] = *(const float4*)(srw + d1);
        *(float4*)&sA[4] = *(const float4*)(srw + d1 + 4);
        *(float4*)&sB[0] = *(const float4*)(srw + d2);
        *(float4*)&sB[4] = *(const float4*)(srw + d2 + 4);
        bf16x8 k1, k2, v1, v2;
#pragma unroll
        for (int j = 0; j < 8; j++) {
          k1[j] = f2bf(xa[j] * cA[j] - xb[j] * sA[j]);
          k2[j] = f2bf(xb[j] * cB[j] + xa[j] * sB[j]);
          v1[j] = f2bf(xa[j]);
          v2[j] = f2bf(xb[j]);
        }
        *(bf16x8*)&Ks[srow * 136 + d1] = k1;
        *(bf16x8*)&Ks[srow * 136 + d2] = k2;
#pragma unroll
        for (int j = 0; j < 8; j++) {
          Vt[(d1 + j) * 80 + srow] = v1[j];
          Vt[(d2 + j) * 80 + srow] = v2[j];
        }
      }
    }
    __syncthreads();

    // S = Q K^T  (64q x 64keys per wave-row-group; wave owns its 16 q rows)
    f32x4 sacc[4] = {};
#pragma unroll
    for (int s = 0; s < 4; s++)
#pragma unroll
      for (int nt = 0; nt < 4; nt++) {
        bf16x8 bk = *(const bf16x8*)&Ks[(nt * 16 + m16) * 136 + s * 32 + quad * 8];
        sacc[nt] = __builtin_amdgcn_mfma_f32_16x16x32_bf16(aq[s], bk, sacc[nt], 0, 0, 0);
      }

    // online softmax (rows are wave-private: no cross-wave reduction)
    float mnew[4], alpha[4];
#pragma unroll
    for (int rg = 0; rg < 4; rg++) {
      float mx = fmaxf(fmaxf(sacc[0][rg], sacc[1][rg]), fmaxf(sacc[2][rg], sacc[3][rg]));
#pragma unroll
      for (int msk = 1; msk < 16; msk <<= 1) mx = fmaxf(mx, __shfl_xor(mx, msk, 16));
      mnew[rg] = fmaxf(mi[rg], mx);
      alpha[rg] = __expf(mi[rg] - mnew[rg]);
      mi[rg] = mnew[rg];
    }
#pragma unroll
    for (int rg = 0; rg < 4; rg++) {
      float rs = 0.f;
#pragma unroll
      for (int nt = 0; nt < 4; nt++) {
        float p = __expf(sacc[nt][rg] - mnew[rg]);
        rs += p;
        Ps[(wave * 16 + quad * 4 + rg) * 72 + nt * 16 + m16] = f2bf(p);
      }
#pragma unroll
      for (int msk = 1; msk < 16; msk <<= 1) rs += __shfl_xor(rs, msk, 16);
      li[rg] = li[rg] * alpha[rg] + rs;
    }
#pragma unroll
    for (int nt = 0; nt < 8; nt++) {
      f32x4 o = oacc[nt];
      o[0] *= alpha[0]; o[1] *= alpha[1]; o[2] *= alpha[2]; o[3] *= alpha[3];
      oacc[nt] = o;
    }

    // O += P V  (P read back in A-layout from wave-private LDS rows)
    bf16x8 ap[2];
#pragma unroll
    for (int s = 0; s < 2; s++)
      ap[s] = *(const bf16x8*)&Ps[(wave * 16 + m16) * 72 + s * 32 + quad * 8];
#pragma unroll
    for (int s = 0; s < 2; s++)
#pragma unroll
      for (int nt = 0; nt < 8; nt++) {
        bf16x8 bv = *(const bf16x8*)&Vt[(nt * 16 + m16) * 80 + s * 32 + quad * 8];
        oacc[nt] = __builtin_amdgcn_mfma_f32_16x16x32_bf16(ap[s], bv, oacc[nt], 0, 0, 0);
      }
  }

  long pbase = (long)(bh * ATT_SPLIT + split) * 64;
#pragma unroll
  for (int nt = 0; nt < 8; nt++)
#pragma unroll
    for (int rg = 0; rg < 4; rg++)
      part[(pbase + wave * 16 + quad * 4 + rg) * 128 + nt * 16 + m16] = oacc[nt][rg];
  if (m16 == 0)
#pragma unroll
    for (int rg = 0; rg < 4; rg++) {
      mstat[pbase + wave * 16 + quad * 4 + rg] = mi[rg];
      lstat[pbase + wave * 16 + quad * 4 + rg] = li[rg];
    }
}

// ---------------- merge the 5 splits ----------------
__global__ __launch_bounds__(128) void attn_merge(
    const float* __restrict__ part, const float* __restrict__ mstat,
    const float* __restrict__ lstat, short* __restrict__ attn) {
  int idx = blockIdx.x;  // bh*64 + q
  int bh = idx >> 6, q = idx & 63;
  int d = threadIdx.x;
  float m5[ATT_SPLIT], l5[ATT_SPLIT];
  float mstar = -INFINITY;
#pragma unroll
  for (int s = 0; s < ATT_SPLIT; s++) {
    m5[s] = mstat[((long)bh * ATT_SPLIT + s) * 64 + q];
    l5[s] = lstat[((long)bh * ATT_SPLIT + s) * 64 + q];
    mstar = fmaxf(mstar, m5[s]);
  }
  float denom = 0.f, o = 0.f;
#pragma unroll
  for (int s = 0; s < ATT_SPLIT; s++) {
    float w = __expf(m5[s] - mstar);
    denom += w * l5[s];
    o += w * part[(((long)bh * ATT_SPLIT + s) * 64 + q) * 128 + d];
  }
  int b = bh >> 5, h = bh & 31;
  attn[(long)(b * 64 + q) * 4096 + h * 128 + d] = f2bf(o / denom);
}

extern "C" void kernel_launch(void* const* d_in, const int* in_sizes, int n_in,
                              void* d_out, int out_size, void* d_ws, size_t ws_size,
                              hipStream_t stream) {
  const float* hs = (const float*)d_in[0];     // (4,64,4096)
  const float* th = (const float*)d_in[1];     // (4,4096,4096)
  const float* cosp = (const float*)d_in[2];   // (4160,128)
  const float* sinp = (const float*)d_in[3];
  const float* wqkv = (const float*)d_in[4];   // (4096,12288)
  const float* wo = (const float*)d_in[5];     // (4096,4096)
  const float* qw = (const float*)d_in[6];     // (128,)
  float* out = (float*)d_out;                  // (4,64,4096) fp32

  char* ws = (char*)d_ws;
  short* WT = (short*)ws;                       // 32 MB (Wq^T then Wo^T, reused)
  float* qtmp = (float*)(ws + (32L << 20));     // 4 MB
  short* qrb = (short*)(ws + (36L << 20));      // 2 MB
  short* attn = (short*)(ws + (38L << 20));     // 2 MB
  float* part = (float*)(ws + (40L << 20));     // 20 MB
  float* mstat = (float*)(ws + (60L << 20));    // 160 KB
  float* lstat = (float*)(ws + (61L << 20));    // 160 KB

  // 1) Wq^T (first 4096 cols of Wqkv only — K/V are not projected)
  transpose_to_bf16<<<dim3(64, 64), 256, 0, stream>>>(wqkv, 12288, WT, 4096);
  // 2) Q = hidden @ Wq
  gemm_bt<true><<<dim3(64, 4), 256, 0, stream>>>(hs, WT, qtmp, 4096, 4096);
  // 3) double RMSNorm + RoPE + 1/sqrt(D) on Q
  q_norm_rope<<<2048, 256, 0, stream>>>(qtmp, qw, cosp, sinp, qrb);
  // 4) flash attention, 5-way key split (K roped in staging, V raw)
  attn_kernel<<<dim3(128, ATT_SPLIT), 256, 0, stream>>>(qrb, th, hs, cosp, sinp,
                                                        part, mstat, lstat);
  // 5) merge splits
  attn_merge<<<128 * 64, 128, 0, stream>>>(part, mstat, lstat, attn);
  // 6) Wo^T
  transpose_to_bf16<<<dim3(64, 64), 256, 0, stream>>>(wo, 4096, WT, 4096);
  // 7) out = attn @ Wo
  gemm_bt<false><<<dim3(64, 4), 256, 0, stream>>>(attn, WT, out, 4096, 4096);
}

// Round 2
// 636.051 us; speedup vs baseline: 1.1410x; 1.1410x over previous
//
#include <hip/hip_runtime.h>

typedef __attribute__((ext_vector_type(8))) short bf16x8;
typedef __attribute__((ext_vector_type(4))) float f32x4;
typedef __attribute__((ext_vector_type(4))) short s16x4;

#define DEV __device__ __forceinline__

DEV short f2bf(float f) {
  union { float f; unsigned u; } v; v.f = f;
  unsigned r = v.u + 0x7fffu + ((v.u >> 16) & 1u);
  return (short)(r >> 16);
}

// ---------------- transpose fp32 -> bf16: out[n][k] = bf16(in[k][n]) ----------------
__global__ __launch_bounds__(256) void transpose_to_bf16(
    const float* __restrict__ in, long ld, short* __restrict__ out, int K) {
  __shared__ short tile[64][66];
  long k0 = blockIdx.x * 64L, n0 = blockIdx.y * 64L;
  int t = threadIdx.x;
  {
    int kl = t >> 4, nl4 = (t & 15) * 4;
#pragma unroll
    for (int i = 0; i < 4; i++) {
      int k = kl + i * 16;
      float4 v = *(const float4*)(in + (k0 + k) * ld + n0 + nl4);
      s16x4 w; w.x = f2bf(v.x); w.y = f2bf(v.y); w.z = f2bf(v.z); w.w = f2bf(v.w);
      *(s16x4*)&tile[k][nl4] = w;
    }
  }
  __syncthreads();
  {
    int nl = t >> 4, kl4 = (t & 15) * 4;
#pragma unroll
    for (int i = 0; i < 4; i++) {
      int n = nl + i * 16;
      s16x4 w;
      w.x = tile[kl4 + 0][n]; w.y = tile[kl4 + 1][n];
      w.z = tile[kl4 + 2][n]; w.w = tile[kl4 + 3][n];
      *(s16x4*)(out + (n0 + n) * (long)K + k0 + kl4) = w;
    }
  }
}

// ---------------- split-K GEMM: Cp[z][M x N] = A[M x Kc@z] * Bt[N x Kc@z]^T --------
// A fp32 (convert on the fly) or bf16; Bt bf16 row-major [N][K]; Cp fp32 partials.
// Block tile 64x64, BK=64, 256 threads (2x2 waves, each wave 32x32).
template <bool AF32>
__global__ __launch_bounds__(256) void gemm_bt_split(
    const void* __restrict__ Ap, const short* __restrict__ Bt,
    float* __restrict__ Cp, int M, int N, int K, int Kc) {
  __shared__ short As[8 * 544];
  __shared__ short Bs[8 * 544];
  int t = threadIdx.x;
  long m0 = blockIdx.y * 64L, n0 = blockIdx.x * 64L;
  int z = blockIdx.z;
  int lane = t & 63, quad = lane >> 4, m16 = lane & 15;
  int wave = t >> 6, wm = wave & 1, wn = wave >> 1;
  f32x4 acc[2][2] = {};
  int r = t >> 3, c = t & 7;  // staging coords: rows 0..31(+32), k-chunks of 8

  int kbeg = z * Kc, kend = kbeg + Kc;
  for (int k0 = kbeg; k0 < kend; k0 += 64) {
    __syncthreads();
#pragma unroll
    for (int half = 0; half < 2; half++) {
      int rr = r + half * 32;
      int fb = (c >> 2) * 4 + (rr >> 4);
      int pos = (c & 3) * 16 + (rr & 15);
      int off = fb * 544 + pos * 8 + (pos >> 4) * 8;  // in shorts
      bf16x8 av;
      if (AF32) {
        const float* src = (const float*)Ap + (m0 + rr) * (long)K + k0 + c * 8;
        float4 x = *(const float4*)src;
        float4 y = *(const float4*)(src + 4);
        av[0] = f2bf(x.x); av[1] = f2bf(x.y); av[2] = f2bf(x.z); av[3] = f2bf(x.w);
        av[4] = f2bf(y.x); av[5] = f2bf(y.y); av[6] = f2bf(y.z); av[7] = f2bf(y.w);
      } else {
        av = *(const bf16x8*)((const short*)Ap + (m0 + rr) * (long)K + k0 + c * 8);
      }
      *(bf16x8*)&As[off] = av;
      *(bf16x8*)&Bs[off] = *(const bf16x8*)(Bt + (n0 + rr) * (long)K + k0 + c * 8);
    }
    __syncthreads();
#pragma unroll
    for (int s = 0; s < 2; s++) {
      int lo = lane * 8 + quad * 8;
      bf16x8 a0 = *(bf16x8*)&As[(s * 4 + wm * 2 + 0) * 544 + lo];
      bf16x8 a1 = *(bf16x8*)&As[(s * 4 + wm * 2 + 1) * 544 + lo];
      bf16x8 b0 = *(bf16x8*)&Bs[(s * 4 + wn * 2 + 0) * 544 + lo];
      bf16x8 b1 = *(bf16x8*)&Bs[(s * 4 + wn * 2 + 1) * 544 + lo];
      acc[0][0] = __builtin_amdgcn_mfma_f32_16x16x32_bf16(a0, b0, acc[0][0], 0, 0, 0);
      acc[0][1] = __builtin_amdgcn_mfma_f32_16x16x32_bf16(a0, b1, acc[0][1], 0, 0, 0);
      acc[1][0] = __builtin_amdgcn_mfma_f32_16x16x32_bf16(a1, b0, acc[1][0], 0, 0, 0);
      acc[1][1] = __builtin_amdgcn_mfma_f32_16x16x32_bf16(a1, b1, acc[1][1], 0, 0, 0);
    }
  }
  float* C = Cp + (long)z * M * N;
#pragma unroll
  for (int i = 0; i < 2; i++)
#pragma unroll
    for (int j = 0; j < 2; j++)
#pragma unroll
      for (int rg = 0; rg < 4; rg++) {
        long m = m0 + (wm * 2 + i) * 16 + quad * 4 + rg;
        long n = n0 + (wn * 2 + j) * 16 + m16;
        C[m * (long)N + n] = acc[i][j][rg];
      }
}

// ---------------- sum 4 split-K partials (float4) ----------------
__global__ __launch_bounds__(256) void reduce4(
    const float* __restrict__ p, float* __restrict__ out, long n4, long stride) {
  long i = (blockIdx.x * 256L + threadIdx.x);
  if (i >= n4) return;
  float4 a = *(const float4*)(p + i * 4);
  float4 b = *(const float4*)(p + stride + i * 4);
  float4 c = *(const float4*)(p + 2 * stride + i * 4);
  float4 d = *(const float4*)(p + 3 * stride + i * 4);
  float4 r;
  r.x = a.x + b.x + c.x + d.x;
  r.y = a.y + b.y + c.y + d.y;
  r.z = a.z + b.z + c.z + d.z;
  r.w = a.w + b.w + c.w + d.w;
  *(float4*)(out + i * 4) = r;
}

// ---------------- double RMSNorm + RoPE + scale on Q (sums 4 K-split partials) -----
// one wave per (row, head); lane holds d and d+64
__global__ __launch_bounds__(256) void q_norm_rope(
    const float* __restrict__ qtmp, const float* __restrict__ qw,
    const float* __restrict__ cosp, const float* __restrict__ sinp,
    short* __restrict__ qr) {
  int wid = blockIdx.x * 4 + (threadIdx.x >> 6);
  int lane = threadIdx.x & 63;
  int rrow = wid >> 5, h = wid & 31;
  long base = (long)rrow * 4096 + h * 128;
  const long STR = 256L * 4096;
  float x1 = qtmp[base + lane] + qtmp[STR + base + lane] +
             qtmp[2 * STR + base + lane] + qtmp[3 * STR + base + lane];
  float x2 = qtmp[base + 64 + lane] + qtmp[STR + base + 64 + lane] +
             qtmp[2 * STR + base + 64 + lane] + qtmp[3 * STR + base + 64 + lane];
  float w1 = qw[lane], w2 = qw[64 + lane];
  float ss = x1 * x1 + x2 * x2;
#pragma unroll
  for (int m = 1; m < 64; m <<= 1) ss += __shfl_xor(ss, m, 64);
  float rs = rsqrtf(ss * (1.0f / 128.0f) + 1e-6f);
  float y1 = x1 * rs * w1, y2 = x2 * rs * w2;
  float ss2 = y1 * y1 + y2 * y2;
#pragma unroll
  for (int m = 1; m < 64; m <<= 1) ss2 += __shfl_xor(ss2, m, 64);
  float rs2 = rsqrtf(ss2 * (1.0f / 128.0f) + 1e-6f);
  float z1 = y1 * rs2 * w1, z2 = y2 * rs2 * w2;
  long cpos = (long)(4096 + (rrow & 63)) * 128;
  float c1 = cosp[cpos + lane], c2 = cosp[cpos + 64 + lane];
  float s1 = sinp[cpos + lane], s2 = sinp[cpos + 64 + lane];
  const float scale = 0.08838834764831845f;  // 1/sqrt(128)
  float o1 = (z1 * c1 - z2 * s1) * scale;
  float o2 = (z2 * c2 + z1 * s2) * scale;
  qr[base + lane] = f2bf(o1);
  qr[base + 64 + lane] = f2bf(o2);
}

// ---------------- flash attention, split-K over key dim ----------------
#define ATT_SPLIT 13
#define ATT_LKV 320
#define ATT_TILES 5

__global__ __launch_bounds__(256) void attn_kernel(
    const short* __restrict__ qr, const float* __restrict__ th,
    const float* __restrict__ hs, const float* __restrict__ cosp,
    const float* __restrict__ sinp, float* __restrict__ part,
    float* __restrict__ mstat, float* __restrict__ lstat) {
  __shared__ short Ks[64 * 136];   // roped K, [l][d], pad 136
  __shared__ short Vt[128 * 80];   // raw V transposed, [d][l], pad 80
  __shared__ short Ps[64 * 72];    // P (C-layout -> A-layout round trip)
  int bh = blockIdx.x, split = blockIdx.y;
  int b = bh >> 5, h = bh & 31;
  int t = threadIdx.x;
  int wave = t >> 6, lane = t & 63, quad = lane >> 4, m16 = lane & 15;

  // Q A-fragments (wave owns q rows wave*16..wave*16+15); Q pre-scaled/roped/normed
  bf16x8 aq[4];
  {
    const short* qrow = qr + (long)(b * 64 + wave * 16 + m16) * 4096 + h * 128;
#pragma unroll
    for (int s = 0; s < 4; s++) aq[s] = *(const bf16x8*)(qrow + s * 32 + quad * 8);
  }
  float mi[4] = {-INFINITY, -INFINITY, -INFINITY, -INFINITY};
  float li[4] = {0.f, 0.f, 0.f, 0.f};
  f32x4 oacc[8] = {};

  int srow = t >> 2;  // staging: 4 threads per key-row
  int sc = t & 3;

  for (int tile = 0; tile < ATT_TILES; tile++) {
    int l0 = split * ATT_LKV + tile * 64;
    __syncthreads();
    {
      int lg = l0 + srow;
      const float* kvrow = (lg < 4096)
          ? th + ((long)b * 4096 + lg) * 4096 + h * 128
          : hs + ((long)b * 64 + (lg - 4096)) * 4096 + h * 128;
      const float* crow = cosp + (long)lg * 128;
      const float* srw = sinp + (long)lg * 128;
#pragma unroll
      for (int i = 0; i < 2; i++) {
        int c = sc + 4 * i;
        int d1 = c * 8, d2 = d1 + 64;
        alignas(16) float xa[8], xb[8], cA[8], sA[8], cB[8], sB[8];
        *(float4*)&xa[0] = *(const float4*)(kvrow + d1);
        *(float4*)&xa[4] = *(const float4*)(kvrow + d1 + 4);
        *(float4*)&xb[0] = *(const float4*)(kvrow + d2);
        *(float4*)&xb[4] = *(const float4*)(kvrow + d2 + 4);
        *(float4*)&cA[0] = *(const float4*)(crow + d1);
        *(float4*)&cA[4] = *(const float4*)(crow + d1 + 4);
        *(float4*)&cB[0] = *(const float4*)(crow + d2);
        *(float4*)&cB[4] = *(const float4*)(crow + d2 + 4);
        *(float4*)&sA[0] = *(const float4*)(srw + d1);
        *(float4*)&sA[4] = *(const float4*)(srw + d1 + 4);
        *(float4*)&sB[0] = *(const float4*)(srw + d2);
        *(float4*)&sB[4] = *(const float4*)(srw + d2 + 4);
        bf16x8 k1, k2, v1, v2;
#pragma unroll
        for (int j = 0; j < 8; j++) {
          k1[j] = f2bf(xa[j] * cA[j] - xb[j] * sA[j]);
          k2[j] = f2bf(xb[j] * cB[j] + xa[j] * sB[j]);
          v1[j] = f2bf(xa[j]);
          v2[j] = f2bf(xb[j]);
        }
        *(bf16x8*)&Ks[srow * 136 + d1] = k1;
        *(bf16x8*)&Ks[srow * 136 + d2] = k2;
#pragma unroll
        for (int j = 0; j < 8; j++) {
          Vt[(d1 + j) * 80 + srow] = v1[j];
          Vt[(d2 + j) * 80 + srow] = v2[j];
        }
      }
    }
    __syncthreads();

    // S = Q K^T  (64q x 64keys; wave owns its 16 q rows)
    f32x4 sacc[4] = {};
#pragma unroll
    for (int s = 0; s < 4; s++)
#pragma unroll
      for (int nt = 0; nt < 4; nt++) {
        bf16x8 bk = *(const bf16x8*)&Ks[(nt * 16 + m16) * 136 + s * 32 + quad * 8];
        sacc[nt] = __builtin_amdgcn_mfma_f32_16x16x32_bf16(aq[s], bk, sacc[nt], 0, 0, 0);
      }

    // online softmax (rows are wave-private: no cross-wave reduction)
    float mnew[4], alpha[4];
#pragma unroll
    for (int rg = 0; rg < 4; rg++) {
      float mx = fmaxf(fmaxf(sacc[0][rg], sacc[1][rg]), fmaxf(sacc[2][rg], sacc[3][rg]));
#pragma unroll
      for (int msk = 1; msk < 16; msk <<= 1) mx = fmaxf(mx, __shfl_xor(mx, msk, 16));
      mnew[rg] = fmaxf(mi[rg], mx);
      alpha[rg] = __expf(mi[rg] - mnew[rg]);
      mi[rg] = mnew[rg];
    }
#pragma unroll
    for (int rg = 0; rg < 4; rg++) {
      float rs = 0.f;
#pragma unroll
      for (int nt = 0; nt < 4; nt++) {
        float p = __expf(sacc[nt][rg] - mnew[rg]);
        rs += p;
        Ps[(wave * 16 + quad * 4 + rg) * 72 + nt * 16 + m16] = f2bf(p);
      }
#pragma unroll
      for (int msk = 1; msk < 16; msk <<= 1) rs += __shfl_xor(rs, msk, 16);
      li[rg] = li[rg] * alpha[rg] + rs;
    }
#pragma unroll
    for (int nt = 0; nt < 8; nt++) {
      f32x4 o = oacc[nt];
      o[0] *= alpha[0]; o[1] *= alpha[1]; o[2] *= alpha[2]; o[3] *= alpha[3];
      oacc[nt] = o;
    }

    // O += P V  (P read back in A-layout from wave-private LDS rows)
    bf16x8 ap[2];
#pragma unroll
    for (int s = 0; s < 2; s++)
      ap[s] = *(const bf16x8*)&Ps[(wave * 16 + m16) * 72 + s * 32 + quad * 8];
#pragma unroll
    for (int s = 0; s < 2; s++)
#pragma unroll
      for (int nt = 0; nt < 8; nt++) {
        bf16x8 bv = *(const bf16x8*)&Vt[(nt * 16 + m16) * 80 + s * 32 + quad * 8];
        oacc[nt] = __builtin_amdgcn_mfma_f32_16x16x32_bf16(ap[s], bv, oacc[nt], 0, 0, 0);
      }
  }

  long pbase = (long)(bh * ATT_SPLIT + split) * 64;
#pragma unroll
  for (int nt = 0; nt < 8; nt++)
#pragma unroll
    for (int rg = 0; rg < 4; rg++)
      part[(pbase + wave * 16 + quad * 4 + rg) * 128 + nt * 16 + m16] = oacc[nt][rg];
  if (m16 == 0)
#pragma unroll
    for (int rg = 0; rg < 4; rg++) {
      mstat[pbase + wave * 16 + quad * 4 + rg] = mi[rg];
      lstat[pbase + wave * 16 + quad * 4 + rg] = li[rg];
    }
}

// ---------------- merge the splits ----------------
__global__ __launch_bounds__(128) void attn_merge(
    const float* __restrict__ part, const float* __restrict__ mstat,
    const float* __restrict__ lstat, short* __restrict__ attn) {
  int idx = blockIdx.x;  // bh*64 + q
  int bh = idx >> 6, q = idx & 63;
  int d = threadIdx.x;
  float mstar = -INFINITY;
#pragma unroll
  for (int s = 0; s < ATT_SPLIT; s++)
    mstar = fmaxf(mstar, mstat[((long)bh * ATT_SPLIT + s) * 64 + q]);
  float denom = 0.f, o = 0.f;
#pragma unroll
  for (int s = 0; s < ATT_SPLIT; s++) {
    long sq = ((long)bh * ATT_SPLIT + s) * 64 + q;
    float w = __expf(mstat[sq] - mstar);
    denom += w * lstat[sq];
    o += w * part[sq * 128 + d];
  }
  int b = bh >> 5, h = bh & 31;
  attn[(long)(b * 64 + q) * 4096 + h * 128 + d] = f2bf(o / denom);
}

extern "C" void kernel_launch(void* const* d_in, const int* in_sizes, int n_in,
                              void* d_out, int out_size, void* d_ws, size_t ws_size,
                              hipStream_t stream) {
  const float* hs = (const float*)d_in[0];     // (4,64,4096)
  const float* th = (const float*)d_in[1];     // (4,4096,4096)
  const float* cosp = (const float*)d_in[2];   // (4160,128)
  const float* sinp = (const float*)d_in[3];
  const float* wqkv = (const float*)d_in[4];   // (4096,12288)
  const float* wo = (const float*)d_in[5];     // (4096,4096)
  const float* qw = (const float*)d_in[6];     // (128,)
  float* out = (float*)d_out;                  // (4,64,4096) fp32

  char* ws = (char*)d_ws;
  short* WT = (short*)ws;                        // 32 MB (Wq^T then Wo^T, reused)
  float* qtmp = (float*)(ws + (32L << 20));      // 16 MB (4 split-K partials)
  short* qrb = (short*)(ws + (48L << 20));       // 2 MB
  short* attn = (short*)(ws + (50L << 20));      // 2 MB
  float* part = (float*)(ws + (52L << 20));      // 54.5 MB (13 splits)
  float* mstat = (float*)(ws + (108L << 20));    // 426 KB
  float* lstat = (float*)(ws + (109L << 20));    // 426 KB
  float* otmp = (float*)(ws + (110L << 20));     // 16 MB (GEMM2 partials)

  // 1) Wq^T (first 4096 cols of Wqkv only — K/V are not projected)
  transpose_to_bf16<<<dim3(64, 64), 256, 0, stream>>>(wqkv, 12288, WT, 4096);
  // 2) Q partials = hidden @ Wq (4-way split-K)
  gemm_bt_split<true><<<dim3(64, 4, 4), 256, 0, stream>>>(hs, WT, qtmp, 256, 4096, 4096, 1024);
  // 3) sum partials + double RMSNorm + RoPE + 1/sqrt(D) on Q
  q_norm_rope<<<2048, 256, 0, stream>>>(qtmp, qw, cosp, sinp, qrb);
  // 4) flash attention, 13-way key split (K roped in staging, V raw)
  attn_kernel<<<dim3(128, ATT_SPLIT), 256, 0, stream>>>(qrb, th, hs, cosp, sinp,
                                                        part, mstat, lstat);
  // 5) merge splits
  attn_merge<<<128 * 64, 128, 0, stream>>>(part, mstat, lstat, attn);
  // 6) Wo^T
  transpose_to_bf16<<<dim3(64, 64), 256, 0, stream>>>(wo, 4096, WT, 4096);
  // 7) out partials = attn @ Wo (4-way split-K)
  gemm_bt_split<false><<<dim3(64, 4, 4), 256, 0, stream>>>(attn, WT, otmp, 256, 4096, 4096, 1024);
  // 8) reduce partials -> out
  reduce4<<<1024, 256, 0, stream>>>(otmp, out, 262144, 1L << 20);
}

// Round 3
// 635.377 us; speedup vs baseline: 1.1422x; 1.0011x over previous
//
#include <hip/hip_runtime.h>

typedef __attribute__((ext_vector_type(8))) short bf16x8;
typedef __attribute__((ext_vector_type(4))) float f32x4;
typedef __attribute__((ext_vector_type(4))) short s16x4;

#define DEV __device__ __forceinline__

DEV short f2bf(float f) {
  union { float f; unsigned u; } v; v.f = f;
  unsigned r = v.u + 0x7fffu + ((v.u >> 16) & 1u);
  return (short)(r >> 16);
}

// packed fp32x2 -> bf16x2 (hardware v_cvt_pk_bf16_f32 on gfx950, RNE)
DEV int pk2(float a, float b) {
#if defined(__has_builtin) && __has_builtin(__builtin_amdgcn_cvt_pk_bf16_f32)
  auto v = __builtin_amdgcn_cvt_pk_bf16_f32(a, b);
  int r; __builtin_memcpy(&r, &v, 4); return r;
#else
  return (int)(unsigned short)f2bf(a) | ((int)(unsigned short)f2bf(b) << 16);
#endif
}

// async global->LDS 16B: lane i's 16B lands at lbase + i*16
DEV void stage16(const short* g, short* lbase, int lane) {
#if defined(__has_builtin) && __has_builtin(__builtin_amdgcn_global_load_lds)
  (void)lane;
  __builtin_amdgcn_global_load_lds((const __attribute__((address_space(1))) void*)g,
                                   (__attribute__((address_space(3))) void*)lbase, 16, 0, 0);
#else
  *(bf16x8*)(lbase + lane * 8) = *(const bf16x8*)g;
#endif
}

// ---------------- transpose fp32 -> bf16: out[n][k] = bf16(in[k][n]) ----------------
__global__ __launch_bounds__(256) void transpose_to_bf16(
    const float* __restrict__ in, long ld, short* __restrict__ out, int K) {
  __shared__ short tile[64][66];
  long k0 = blockIdx.x * 64L, n0 = blockIdx.y * 64L;
  int t = threadIdx.x;
  {
    int kl = t >> 4, nl4 = (t & 15) * 4;
#pragma unroll
    for (int i = 0; i < 4; i++) {
      int k = kl + i * 16;
      float4 v = *(const float4*)(in + (k0 + k) * ld + n0 + nl4);
      int* dst = (int*)&tile[k][nl4];
      dst[0] = pk2(v.x, v.y);
      dst[1] = pk2(v.z, v.w);
    }
  }
  __syncthreads();
  {
    int nl = t >> 4, kl4 = (t & 15) * 4;
#pragma unroll
    for (int i = 0; i < 4; i++) {
      int n = nl + i * 16;
      s16x4 w;
      w.x = tile[kl4 + 0][n]; w.y = tile[kl4 + 1][n];
      w.z = tile[kl4 + 2][n]; w.w = tile[kl4 + 3][n];
      *(s16x4*)(out + (n0 + n) * (long)K + k0 + kl4) = w;
    }
  }
}

// ---------------- cast fp32 -> bf16 (8 elems/thread) ----------------
__global__ __launch_bounds__(256) void cast_f32_bf16(
    const float* __restrict__ in, short* __restrict__ out, int n8) {
  int i = blockIdx.x * 256 + threadIdx.x;
  if (i >= n8) return;
  float4 a = *(const float4*)(in + (long)i * 8);
  float4 b = *(const float4*)(in + (long)i * 8 + 4);
  union { bf16x8 v; int w[4]; } r;
  r.w[0] = pk2(a.x, a.y); r.w[1] = pk2(a.z, a.w);
  r.w[2] = pk2(b.x, b.y); r.w[3] = pk2(b.z, b.w);
  *(bf16x8*)(out + (long)i * 8) = r.v;
}

// ---------------- split-K GEMM, M=256 full tile, N-tile 64, BK=64, DMA staging -----
// A bf16 [256][K]; Bt bf16 [N][K]; Cp fp32 partials [z][256][N].
// 8 waves; wave w computes rows 32w..32w+31 x all 64 cols.
// LDS fragment-ordered 1KB blocks, filled by global_load_lds (16B/lane).
__global__ __launch_bounds__(512) void gemm_dma(
    const short* __restrict__ A, const short* __restrict__ Bt,
    float* __restrict__ Cp, int N, int K, int Kc) {
  __shared__ short As[32 * 512];
  __shared__ short Bs[8 * 512];
  int t = threadIdx.x;
  int lane = t & 63, wave = t >> 6;
  int quad = lane >> 4, m16 = lane & 15;
  long n0 = blockIdx.x * 64L;
  int z = blockIdx.y;
  f32x4 acc[2][4] = {};
  int kbeg = z * Kc, kend = kbeg + Kc;

  for (int k0 = kbeg; k0 < kend; k0 += 64) {
    __syncthreads();
#pragma unroll
    for (int i = 0; i < 2; i++)
#pragma unroll
      for (int s = 0; s < 2; s++) {
        int row = (2 * wave + i) * 16 + m16;
        const short* g = A + (long)row * K + k0 + (s * 4 + quad) * 8;
        stage16(g, &As[(4 * wave + 2 * i + s) * 512], lane);
      }
    {
      int nt = wave >> 1, s = wave & 1;
      long row = n0 + nt * 16 + m16;
      const short* g = Bt + row * (long)K + k0 + (s * 4 + quad) * 8;
      stage16(g, &Bs[wave * 512], lane);
    }
    __syncthreads();
#pragma unroll
    for (int s = 0; s < 2; s++) {
      bf16x8 a0 = *(bf16x8*)&As[(4 * wave + s) * 512 + lane * 8];
      bf16x8 a1 = *(bf16x8*)&As[(4 * wave + 2 + s) * 512 + lane * 8];
#pragma unroll
      for (int nt = 0; nt < 4; nt++) {
        bf16x8 b = *(bf16x8*)&Bs[(nt * 2 + s) * 512 + lane * 8];
        acc[0][nt] = __builtin_amdgcn_mfma_f32_16x16x32_bf16(a0, b, acc[0][nt], 0, 0, 0);
        acc[1][nt] = __builtin_amdgcn_mfma_f32_16x16x32_bf16(a1, b, acc[1][nt], 0, 0, 0);
      }
    }
  }
  float* C = Cp + (long)z * 256 * N;
#pragma unroll
  for (int i = 0; i < 2; i++)
#pragma unroll
    for (int nt = 0; nt < 4; nt++)
#pragma unroll
      for (int rg = 0; rg < 4; rg++) {
        long m = (2 * wave + i) * 16 + quad * 4 + rg;
        C[m * (long)N + n0 + nt * 16 + m16] = acc[i][nt][rg];
      }
}

// ---------------- sum 8 split-K partials (float4) ----------------
__global__ __launch_bounds__(256) void reduce8(
    const float* __restrict__ p, float* __restrict__ out, long n4, long stride) {
  long i = (blockIdx.x * 256L + threadIdx.x);
  if (i >= n4) return;
  float4 r = *(const float4*)(p + i * 4);
#pragma unroll
  for (int z = 1; z < 8; z++) {
    float4 a = *(const float4*)(p + z * stride + i * 4);
    r.x += a.x; r.y += a.y; r.z += a.z; r.w += a.w;
  }
  *(float4*)(out + i * 4) = r;
}

// ---------------- double RMSNorm + RoPE + scale on Q (sums 8 K-split partials) -----
__global__ __launch_bounds__(256) void q_norm_rope(
    const float* __restrict__ qtmp, const float* __restrict__ qw,
    const float* __restrict__ cosp, const float* __restrict__ sinp,
    short* __restrict__ qr) {
  int wid = blockIdx.x * 4 + (threadIdx.x >> 6);
  int lane = threadIdx.x & 63;
  int rrow = wid >> 5, h = wid & 31;
  long base = (long)rrow * 4096 + h * 128;
  const long STR = 256L * 4096;
  float x1 = 0.f, x2 = 0.f;
#pragma unroll
  for (int z = 0; z < 8; z++) {
    x1 += qtmp[z * STR + base + lane];
    x2 += qtmp[z * STR + base + 64 + lane];
  }
  float w1 = qw[lane], w2 = qw[64 + lane];
  float ss = x1 * x1 + x2 * x2;
#pragma unroll
  for (int m = 1; m < 64; m <<= 1) ss += __shfl_xor(ss, m, 64);
  float rs = rsqrtf(ss * (1.0f / 128.0f) + 1e-6f);
  float y1 = x1 * rs * w1, y2 = x2 * rs * w2;
  float ss2 = y1 * y1 + y2 * y2;
#pragma unroll
  for (int m = 1; m < 64; m <<= 1) ss2 += __shfl_xor(ss2, m, 64);
  float rs2 = rsqrtf(ss2 * (1.0f / 128.0f) + 1e-6f);
  float z1 = y1 * rs2 * w1, z2 = y2 * rs2 * w2;
  long cpos = (long)(4096 + (rrow & 63)) * 128;
  float c1 = cosp[cpos + lane], c2 = cosp[cpos + 64 + lane];
  float s1 = sinp[cpos + lane], s2 = sinp[cpos + 64 + lane];
  const float scale = 0.08838834764831845f;  // 1/sqrt(128)
  float o1 = (z1 * c1 - z2 * s1) * scale;
  float o2 = (z2 * c2 + z1 * s2) * scale;
  qr[base + lane] = f2bf(o1);
  qr[base + 64 + lane] = f2bf(o2);
}

// ---------------- flash attention, split-K over key dim ----------------
#define ATT_SPLIT 13
#define ATT_LKV 320
#define ATT_TILES 5

__global__ __launch_bounds__(256) void attn_kernel(
    const short* __restrict__ qr, const float* __restrict__ th,
    const float* __restrict__ hs, const float* __restrict__ cosp,
    const float* __restrict__ sinp, float* __restrict__ part,
    float* __restrict__ mstat, float* __restrict__ lstat) {
  __shared__ short Ks[64 * 136];   // roped K, [l][d], pad 136
  __shared__ short Vt[128 * 80];   // raw V transposed, [d][l^swz], pad 80
  __shared__ short Ps[64 * 72];    // P (C-layout -> A-layout round trip)
  int bh = blockIdx.x, split = blockIdx.y;
  int b = bh >> 5, h = bh & 31;
  int t = threadIdx.x;
  int wave = t >> 6, lane = t & 63, quad = lane >> 4, m16 = lane & 15;

  bf16x8 aq[4];
  {
    const short* qrow = qr + (long)(b * 64 + wave * 16 + m16) * 4096 + h * 128;
#pragma unroll
    for (int s = 0; s < 4; s++) aq[s] = *(const bf16x8*)(qrow + s * 32 + quad * 8);
  }
  float mi[4] = {-INFINITY, -INFINITY, -INFINITY, -INFINITY};
  float li[4] = {0.f, 0.f, 0.f, 0.f};
  f32x4 oacc[8] = {};

  int srow = t >> 2;  // staging: 4 threads per key-row
  int sc = t & 3;
  int colw = srow ^ (sc * 16);  // XOR swizzle: breaks sc-lane bank aliasing

  for (int tile = 0; tile < ATT_TILES; tile++) {
    int l0 = split * ATT_LKV + tile * 64;
    __syncthreads();
    {
      int lg = l0 + srow;
      const float* kvrow = (lg < 4096)
          ? th + ((long)b * 4096 + lg) * 4096 + h * 128
          : hs + ((long)b * 64 + (lg - 4096)) * 4096 + h * 128;
      const float* crow = cosp + (long)lg * 128;
      const float* srw = sinp + (long)lg * 128;
#pragma unroll
      for (int i = 0; i < 2; i++) {
        int c = sc + 4 * i;
        int d1 = c * 8, d2 = d1 + 64;
        alignas(16) float xa[8], xb[8], cA[8], sA[8], cB[8], sB[8];
        *(float4*)&xa[0] = *(const float4*)(kvrow + d1);
        *(float4*)&xa[4] = *(const float4*)(kvrow + d1 + 4);
        *(float4*)&xb[0] = *(const float4*)(kvrow + d2);
        *(float4*)&xb[4] = *(const float4*)(kvrow + d2 + 4);
        *(float4*)&cA[0] = *(const float4*)(crow + d1);
        *(float4*)&cA[4] = *(const float4*)(crow + d1 + 4);
        *(float4*)&cB[0] = *(const float4*)(crow + d2);
        *(float4*)&cB[4] = *(const float4*)(crow + d2 + 4);
        *(float4*)&sA[0] = *(const float4*)(srw + d1);
        *(float4*)&sA[4] = *(const float4*)(srw + d1 + 4);
        *(float4*)&sB[0] = *(const float4*)(srw + d2);
        *(float4*)&sB[4] = *(const float4*)(srw + d2 + 4);
        union { bf16x8 v; int w[4]; } K1, K2;
#pragma unroll
        for (int jj = 0; jj < 4; jj++) {
          int j0 = 2 * jj, j1 = 2 * jj + 1;
          K1.w[jj] = pk2(xa[j0] * cA[j0] - xb[j0] * sA[j0],
                         xa[j1] * cA[j1] - xb[j1] * sA[j1]);
          K2.w[jj] = pk2(xb[j0] * cB[j0] + xa[j0] * sB[j0],
                         xb[j1] * cB[j1] + xa[j1] * sB[j1]);
        }
        *(bf16x8*)&Ks[srow * 136 + d1] = K1.v;
        *(bf16x8*)&Ks[srow * 136 + d2] = K2.v;
#pragma unroll
        for (int jj = 0; jj < 4; jj++) {
          int p1 = pk2(xa[2 * jj], xa[2 * jj + 1]);
          int p2 = pk2(xb[2 * jj], xb[2 * jj + 1]);
          Vt[(d1 + 2 * jj) * 80 + colw] = (short)(p1 & 0xffff);
          Vt[(d1 + 2 * jj + 1) * 80 + colw] = (short)((unsigned)p1 >> 16);
          Vt[(d2 + 2 * jj) * 80 + colw] = (short)(p2 & 0xffff);
          Vt[(d2 + 2 * jj + 1) * 80 + colw] = (short)((unsigned)p2 >> 16);
        }
      }
    }
    __syncthreads();

    // S = Q K^T
    f32x4 sacc[4] = {};
#pragma unroll
    for (int s = 0; s < 4; s++)
#pragma unroll
      for (int nt = 0; nt < 4; nt++) {
        bf16x8 bk = *(const bf16x8*)&Ks[(nt * 16 + m16) * 136 + s * 32 + quad * 8];
        sacc[nt] = __builtin_amdgcn_mfma_f32_16x16x32_bf16(aq[s], bk, sacc[nt], 0, 0, 0);
      }

    // online softmax (rows are wave-private)
    float mnew[4], alpha[4];
#pragma unroll
    for (int rg = 0; rg < 4; rg++) {
      float mx = fmaxf(fmaxf(sacc[0][rg], sacc[1][rg]), fmaxf(sacc[2][rg], sacc[3][rg]));
#pragma unroll
      for (int msk = 1; msk < 16; msk <<= 1) mx = fmaxf(mx, __shfl_xor(mx, msk, 16));
      mnew[rg] = fmaxf(mi[rg], mx);
      alpha[rg] = __expf(mi[rg] - mnew[rg]);
      mi[rg] = mnew[rg];
    }
#pragma unroll
    for (int rg = 0; rg < 4; rg++) {
      float rs = 0.f;
#pragma unroll
      for (int nt = 0; nt < 4; nt++) {
        float p = __expf(sacc[nt][rg] - mnew[rg]);
        rs += p;
        Ps[(wave * 16 + quad * 4 + rg) * 72 + nt * 16 + m16] = f2bf(p);
      }
#pragma unroll
      for (int msk = 1; msk < 16; msk <<= 1) rs += __shfl_xor(rs, msk, 16);
      li[rg] = li[rg] * alpha[rg] + rs;
    }
#pragma unroll
    for (int nt = 0; nt < 8; nt++) {
      f32x4 o = oacc[nt];
      o[0] *= alpha[0]; o[1] *= alpha[1]; o[2] *= alpha[2]; o[3] *= alpha[3];
      oacc[nt] = o;
    }

    // O += P V
    bf16x8 ap[2];
#pragma unroll
    for (int s = 0; s < 2; s++)
      ap[s] = *(const bf16x8*)&Ps[(wave * 16 + m16) * 72 + s * 32 + quad * 8];
#pragma unroll
    for (int s = 0; s < 2; s++)
#pragma unroll
      for (int nt = 0; nt < 8; nt++) {
        int d16 = nt * 16 + m16;
        int scd = (d16 >> 3) & 3;
        int cb = (s * 32 + quad * 8) ^ (scd * 16);
        bf16x8 bv = *(const bf16x8*)&Vt[d16 * 80 + cb];
        oacc[nt] = __builtin_amdgcn_mfma_f32_16x16x32_bf16(ap[s], bv, oacc[nt], 0, 0, 0);
      }
  }

  long pbase = (long)(bh * ATT_SPLIT + split) * 64;
#pragma unroll
  for (int nt = 0; nt < 8; nt++)
#pragma unroll
    for (int rg = 0; rg < 4; rg++)
      part[(pbase + wave * 16 + quad * 4 + rg) * 128 + nt * 16 + m16] = oacc[nt][rg];
  if (m16 == 0)
#pragma unroll
    for (int rg = 0; rg < 4; rg++) {
      mstat[pbase + wave * 16 + quad * 4 + rg] = mi[rg];
      lstat[pbase + wave * 16 + quad * 4 + rg] = li[rg];
    }
}

// ---------------- merge the splits ----------------
__global__ __launch_bounds__(128) void attn_merge(
    const float* __restrict__ part, const float* __restrict__ mstat,
    const float* __restrict__ lstat, short* __restrict__ attn) {
  int idx = blockIdx.x;  // bh*64 + q
  int bh = idx >> 6, q = idx & 63;
  int d = threadIdx.x;
  float mstar = -INFINITY;
#pragma unroll
  for (int s = 0; s < ATT_SPLIT; s++)
    mstar = fmaxf(mstar, mstat[((long)bh * ATT_SPLIT + s) * 64 + q]);
  float denom = 0.f, o = 0.f;
#pragma unroll
  for (int s = 0; s < ATT_SPLIT; s++) {
    long sq = ((long)bh * ATT_SPLIT + s) * 64 + q;
    float w = __expf(mstat[sq] - mstar);
    denom += w * lstat[sq];
    o += w * part[sq * 128 + d];
  }
  int b = bh >> 5, h = bh & 31;
  attn[(long)(b * 64 + q) * 4096 + h * 128 + d] = f2bf(o / denom);
}

extern "C" void kernel_launch(void* const* d_in, const int* in_sizes, int n_in,
                              void* d_out, int out_size, void* d_ws, size_t ws_size,
                              hipStream_t stream) {
  const float* hs = (const float*)d_in[0];     // (4,64,4096)
  const float* th = (const float*)d_in[1];     // (4,4096,4096)
  const float* cosp = (const float*)d_in[2];   // (4160,128)
  const float* sinp = (const float*)d_in[3];
  const float* wqkv = (const float*)d_in[4];   // (4096,12288)
  const float* wo = (const float*)d_in[5];     // (4096,4096)
  const float* qw = (const float*)d_in[6];     // (128,)
  float* out = (float*)d_out;                  // (4,64,4096) fp32

  char* ws = (char*)d_ws;
  short* WT   = (short*)ws;                      // 32 MB (Wq^T then Wo^T, reused)
  short* hsb  = (short*)(ws + (32L << 20));      // 2 MB  bf16 hidden_states
  float* qtmp = (float*)(ws + (34L << 20));      // 32 MB (8 split-K partials)
  short* qrb  = (short*)(ws + (66L << 20));      // 2 MB
  short* attnb= (short*)(ws + (68L << 20));      // 2 MB
  float* part = (float*)(ws + (70L << 20));      // 54.5 MB (13 splits)
  float* mstat= (float*)(ws + (125L << 20));     // 426 KB
  float* lstat= (float*)(ws + (126L << 20));     // 426 KB
  float* otmp = (float*)(ws + (127L << 20));     // 32 MB (GEMM2 partials)

  // 1) Wq^T (first 4096 cols of Wqkv — K/V are not projected)
  transpose_to_bf16<<<dim3(64, 64), 256, 0, stream>>>(wqkv, 12288, WT, 4096);
  // 2) hs -> bf16
  cast_f32_bf16<<<512, 256, 0, stream>>>(hs, hsb, 131072);
  // 3) Q partials = hs @ Wq (8-way split-K, DMA-staged MFMA)
  gemm_dma<<<dim3(64, 8), 512, 0, stream>>>(hsb, WT, qtmp, 4096, 4096, 512);
  // 4) sum partials + double RMSNorm + RoPE + 1/sqrt(D)
  q_norm_rope<<<2048, 256, 0, stream>>>(qtmp, qw, cosp, sinp, qrb);
  // 5) flash attention, 13-way key split
  attn_kernel<<<dim3(128, ATT_SPLIT), 256, 0, stream>>>(qrb, th, hs, cosp, sinp,
                                                        part, mstat, lstat);
  // 6) merge splits
  attn_merge<<<128 * 64, 128, 0, stream>>>(part, mstat, lstat, attnb);
  // 7) Wo^T
  transpose_to_bf16<<<dim3(64, 64), 256, 0, stream>>>(wo, 4096, WT, 4096);
  // 8) out partials = attn @ Wo (8-way split-K)
  gemm_dma<<<dim3(64, 8), 512, 0, stream>>>(attnb, WT, otmp, 4096, 4096, 512);
  // 9) reduce partials -> out
  reduce8<<<1024, 256, 0, stream>>>(otmp, out, 262144, 1048576);
}